// Round 1
// baseline (2994.638 us; speedup 1.0000x reference)
//
#include <hip/hip_runtime.h>
#include <hip/hip_bf16.h>
#include <stdint.h>

#define E_ 8
#define C_ 2048
#define D_ 2048
#define F_ 8192

typedef __bf16 bf16x8 __attribute__((ext_vector_type(8)));
typedef float floatx4 __attribute__((ext_vector_type(4)));
typedef uint32_t uint32x4 __attribute__((ext_vector_type(4)));

__device__ __forceinline__ uint16_t f2bf_rne(float f) {
    uint32_t u = __builtin_bit_cast(uint32_t, f);
    u += 0x7fffu + ((u >> 16) & 1u);
    return (uint16_t)(u >> 16);
}

__device__ __forceinline__ float gelu_tanh(float x) {
    // JAX default gelu (approximate=True): 0.5x(1+tanh(0.79788456(x+0.044715x^3)))
    float z = 0.7978845608028654f * x * (1.0f + 0.044715f * x * x);
    float e = __expf(2.0f * z);
    float t = 1.0f - 2.0f / (e + 1.0f);
    return 0.5f * x * (1.0f + t);
}

// ---------------- X: fp32 -> bf16, 8 elems/thread ----------------
__global__ __launch_bounds__(256) void convert_x_kernel(const float* __restrict__ in,
                                                        uint16_t* __restrict__ out, int n8) {
    int i = blockIdx.x * 256 + threadIdx.x;
    if (i >= n8) return;
    const floatx4* pin = (const floatx4*)in;
    floatx4 a = pin[2 * i];
    floatx4 b = pin[2 * i + 1];
    uint32x4 w;
    w[0] = (uint32_t)f2bf_rne(a[0]) | ((uint32_t)f2bf_rne(a[1]) << 16);
    w[1] = (uint32_t)f2bf_rne(a[2]) | ((uint32_t)f2bf_rne(a[3]) << 16);
    w[2] = (uint32_t)f2bf_rne(b[0]) | ((uint32_t)f2bf_rne(b[1]) << 16);
    w[3] = (uint32_t)f2bf_rne(b[2]) | ((uint32_t)f2bf_rne(b[3]) << 16);
    ((uint32x4*)out)[i] = w;
}

// ---------------- per-expert [K,N] fp32 -> [N,K] bf16 ----------------
// 64x64 tiles through LDS; pad=65 keeps both phases <=2-way bank aliased (free).
__global__ __launch_bounds__(256) void transpose_convert_kernel(
    const float* __restrict__ in, uint16_t* __restrict__ out,
    int K, int N, int tiles_k, int tiles_n) {
    __shared__ float lds[64 * 65];
    int tiles = tiles_k * tiles_n;
    int e = blockIdx.x / tiles;
    int t = blockIdx.x % tiles;
    int tk = t % tiles_k;
    int tn = t / tiles_k;
    size_t ebase = (size_t)e * K * N;
    int k0 = tk * 64, n0 = tn * 64;
    const float* ip = in + ebase + (size_t)k0 * N + n0;
    int tid = threadIdx.x;
#pragma unroll
    for (int i = 0; i < 4; i++) {
        int lin = i * 256 + tid;
        int r = lin >> 4, c = lin & 15;
        floatx4 v = *(const floatx4*)(ip + (size_t)r * N + c * 4);
        float* l = &lds[r * 65 + c * 4];
        l[0] = v[0]; l[1] = v[1]; l[2] = v[2]; l[3] = v[3];
    }
    __syncthreads();
    uint16_t* op = out + ebase + (size_t)n0 * K + k0;
#pragma unroll
    for (int i = 0; i < 2; i++) {
        int lin = i * 256 + tid;
        int n = lin >> 3, c = lin & 7;
        uint32x4 w;
#pragma unroll
        for (int j = 0; j < 4; j++) {
            float f0 = lds[(c * 8 + 2 * j) * 65 + n];
            float f1 = lds[(c * 8 + 2 * j + 1) * 65 + n];
            w[j] = (uint32_t)f2bf_rne(f0) | ((uint32_t)f2bf_rne(f1) << 16);
        }
        *(uint32x4*)(op + (size_t)n * K + c * 8) = w;
    }
}

// ---------------- m97-style bf16 GEMM: C[M,N] = A[M,K] @ Bt[N,K]^T ----------------
// 128x128 tile / 256 threads (4 waves, each 64x64 = 4x4 of 16x16x32 MFMA), BK=64,
// global_load_lds width-16 staging. GELU template arg fuses gelu+bf16 store (GEMM1)
// vs fp32 store (GEMM2). Bias added in epilogue.
template <int GELU>
__global__ __launch_bounds__(256) void gemm_bt_kernel(
    const uint16_t* __restrict__ A,   // [E][M][K] bf16
    const uint16_t* __restrict__ Bt,  // [E][N][K] bf16
    const float* __restrict__ bias,   // [E][N]
    void* __restrict__ Out,           // [E][M][N] bf16 if GELU else fp32
    int M, int N, int K, int tiles_m, int tiles_n) {
    __shared__ uint16_t As[128 * 64];
    __shared__ uint16_t Bs[128 * 64];
    int tiles = tiles_m * tiles_n;
    int e = blockIdx.x / tiles;
    int t = blockIdx.x % tiles;
    int bm = t % tiles_m;   // m-fastest: consecutive blocks share the B tile (L2)
    int bn = t / tiles_m;
    int tid = threadIdx.x;
    int lane = tid & 63;
    int wid = tid >> 6;
    int wm = wid >> 1, wn = wid & 1;

    const uint16_t* Ae = A + (size_t)e * M * K;
    const uint16_t* Be = Bt + (size_t)e * N * K;

    // staging: chunk ch (0..15) = 8 rows x 64 k = 1KB; lane -> row ch*8+lane/8, k (lane%8)*8
    int srow = lane >> 3;
    int skk = (lane & 7) * 8;
    const uint16_t* ag[4];
    const uint16_t* bg[4];
#pragma unroll
    for (int j = 0; j < 4; j++) {
        int ch = wid * 4 + j;
        ag[j] = Ae + (size_t)(bm * 128 + ch * 8 + srow) * K + skk;
        bg[j] = Be + (size_t)(bn * 128 + ch * 8 + srow) * K + skk;
    }

    floatx4 acc[4][4];
#pragma unroll
    for (int i = 0; i < 4; i++)
#pragma unroll
        for (int j = 0; j < 4; j++)
#pragma unroll
            for (int r = 0; r < 4; r++) acc[i][j][r] = 0.0f;

    int aoff[4], boff[4];
#pragma unroll
    for (int i = 0; i < 4; i++) {
        aoff[i] = (wm * 64 + i * 16 + (lane & 15)) * 64 + (lane >> 4) * 8;
        boff[i] = (wn * 64 + i * 16 + (lane & 15)) * 64 + (lane >> 4) * 8;
    }

    int kt = K >> 6;
    for (int k0 = 0; k0 < kt; k0++) {
#pragma unroll
        for (int j = 0; j < 4; j++) {
            __builtin_amdgcn_global_load_lds(
                (const __attribute__((address_space(1))) uint32_t*)ag[j],
                (__attribute__((address_space(3))) uint32_t*)&As[(wid * 4 + j) * 512], 16, 0, 0);
            __builtin_amdgcn_global_load_lds(
                (const __attribute__((address_space(1))) uint32_t*)bg[j],
                (__attribute__((address_space(3))) uint32_t*)&Bs[(wid * 4 + j) * 512], 16, 0, 0);
            ag[j] += 64;
            bg[j] += 64;
        }
        __syncthreads();
#pragma unroll
        for (int ks = 0; ks < 2; ks++) {
            bf16x8 fa[4], fb[4];
#pragma unroll
            for (int i = 0; i < 4; i++) {
                fa[i] = *(const bf16x8*)&As[aoff[i] + ks * 32];
                fb[i] = *(const bf16x8*)&Bs[boff[i] + ks * 32];
            }
#pragma unroll
            for (int i = 0; i < 4; i++)
#pragma unroll
                for (int j = 0; j < 4; j++)
                    acc[i][j] = __builtin_amdgcn_mfma_f32_16x16x32_bf16(fa[i], fb[j], acc[i][j], 0, 0, 0);
        }
        __syncthreads();
    }

    // epilogue: C/D layout col=lane&15, row=(lane>>4)*4+r (m89-verified)
    int col0 = bn * 128 + wn * 64 + (lane & 15);
    int row0 = bm * 128 + wm * 64 + (lane >> 4) * 4;
    const float* be = bias + (size_t)e * N;
    if (GELU) {
        uint16_t* O = (uint16_t*)Out + (size_t)e * M * N;
#pragma unroll
        for (int j = 0; j < 4; j++) {
            int col = col0 + j * 16;
            float bv = be[col];
#pragma unroll
            for (int i = 0; i < 4; i++) {
                int row = row0 + i * 16;
#pragma unroll
                for (int r = 0; r < 4; r++) {
                    float v = acc[i][j][r] + bv;
                    O[(size_t)(row + r) * N + col] = f2bf_rne(gelu_tanh(v));
                }
            }
        }
    } else {
        float* O = (float*)Out + (size_t)e * M * N;
#pragma unroll
        for (int j = 0; j < 4; j++) {
            int col = col0 + j * 16;
            float bv = be[col];
#pragma unroll
            for (int i = 0; i < 4; i++) {
                int row = row0 + i * 16;
#pragma unroll
                for (int r = 0; r < 4; r++) {
                    O[(size_t)(row + r) * N + col] = acc[i][j][r] + bv;
                }
            }
        }
    }
}

extern "C" void kernel_launch(void* const* d_in, const int* in_sizes, int n_in,
                              void* d_out, int out_size, void* d_ws, size_t ws_size,
                              hipStream_t stream) {
    (void)in_sizes; (void)n_in; (void)out_size; (void)ws_size;
    const float* x  = (const float*)d_in[0];
    const float* w1 = (const float*)d_in[1];
    const float* b1 = (const float*)d_in[2];
    const float* w2 = (const float*)d_in[3];
    const float* b2 = (const float*)d_in[4];
    float* out = (float*)d_out;

    // workspace layout (bf16): Xb 64M, Wt 256M (W1t then reused for W2t), Hb 256M
    uint16_t* Xb = (uint16_t*)d_ws;                    // E*C*D
    uint16_t* Wt = Xb + (size_t)E_ * C_ * D_;          // max(E*D*F, E*F*D)
    uint16_t* Hb = Wt + (size_t)E_ * D_ * F_;          // E*C*F

    int n8 = (E_ * C_ * D_) / 8;
    convert_x_kernel<<<n8 / 256, 256, 0, stream>>>(x, Xb, n8);

    // W1 [E][D][F] -> W1t [E][F][D]
    transpose_convert_kernel<<<E_ * (D_ / 64) * (F_ / 64), 256, 0, stream>>>(
        w1, Wt, D_, F_, D_ / 64, F_ / 64);

    // H = gelu(X @ W1 + b1), bf16
    gemm_bt_kernel<1><<<E_ * (C_ / 128) * (F_ / 128), 256, 0, stream>>>(
        Xb, Wt, b1, Hb, C_, F_, D_, C_ / 128, F_ / 128);

    // W2 [E][F][D] -> W2t [E][D][F] (reuses Wt after GEMM1 completes; stream-serialized)
    transpose_convert_kernel<<<E_ * (F_ / 64) * (D_ / 64), 256, 0, stream>>>(
        w2, Wt, F_, D_, F_ / 64, D_ / 64);

    // Out = H @ W2 + b2, fp32
    gemm_bt_kernel<0><<<E_ * (C_ / 128) * (D_ / 128), 256, 0, stream>>>(
        Hb, Wt, b2, out, C_, D_, F_, C_ / 128, D_ / 128);
}